// Round 10
// baseline (415.156 us; speedup 1.0000x reference)
//
#include <hip/hip_runtime.h>
#include <hip/hip_bf16.h>
#include <math.h>

#define NP   19000      // NUM_PROTEINS
#define ND   1024       // NUM_DRUGS
#define CHN  256        // IN_CH == EMBED
#define ESG  1500000    // E_SG
#define NSG  800000     // N_SG
#define BDD  4096       // B_DD

#define GEMM_BX   ((NP + 63) / 64)       // 297 row-panels
#define GEMM_SW_G ((GEMM_BX + 7) / 8)    // 38 groups of 8 panels (one per XCD)
#define GEMM_SW_BLK (GEMM_SW_G * 8 * 4)  // 1216 swizzled gemm blocks (28 dummies)
#define FILL_BLK  ((ESG + 255) / 256)    // 5860

#define NCH  256                          // edge chunks for counting sort
#define ECH  ((ESG + NCH - 1) / NCH)      // 5860 edges per chunk
#define DP_BLKS (((ND + 1) + 255) / 256)  // 5 drug_ptr blocks

typedef __attribute__((ext_vector_type(8))) short bf16x8;           // 8 bf16 = 4 VGPR
typedef __attribute__((ext_vector_type(8))) unsigned short u16x8;   // 16B gather
typedef __attribute__((ext_vector_type(4))) float f32x4;            // MFMA acc
typedef __attribute__((ext_vector_type(2))) float f32x2;            // packed-f32 pair

// ---------------------------------------------------------------- bf16 helpers (raw ushort)
static __device__ __forceinline__ unsigned short f2bf(float f) {
    unsigned u = __float_as_uint(f);
    u = u + 0x7fffu + ((u >> 16) & 1u);        // round-to-nearest-even
    return (unsigned short)(u >> 16);
}
static __device__ __forceinline__ float bf2f(unsigned short h) {
    return __uint_as_float((unsigned)h << 16);
}
// u32 of 2 bf16 -> f32 pair (ch 2j, 2j+1); feeds v_pk_add/v_pk_fma
static __device__ __forceinline__ f32x2 bfpair(unsigned w) {
    f32x2 r;
    r.x = __uint_as_float(w << 16);
    r.y = __uint_as_float(w & 0xffff0000u);
    return r;
}
// fp32x8 -> bf16 hi/lo split, in-register
static __device__ __forceinline__ void cvt8(float4 v0, float4 v1, bf16x8& h8, bf16x8& l8) {
    float vv[8] = {v0.x, v0.y, v0.z, v0.w, v1.x, v1.y, v1.z, v1.w};
#pragma unroll
    for (int i = 0; i < 8; i++) {
        unsigned short h = f2bf(vv[i]);
        h8[i] = (short)h;
        l8[i] = (short)f2bf(vv[i] - bf2f(h));
    }
}

// ---------------------------------------------------------------- utilities
static __device__ __forceinline__ int lower_bound_dev(const int* __restrict__ arr, int n, int val) {
    int lo = 0, hi = n;
    while (lo < hi) {
        int mid = (lo + hi) >> 1;
        if (arr[mid] < val) lo = mid + 1; else hi = mid;
    }
    return lo;
}

// ---------------------------------------------------------------- chunked counting sort, pass 1
// Streaming loads/stores marked non-temporal: dst/rank are read/written once;
// keeps L2 free for the hot tables used by neighboring kernels.
__global__ __launch_bounds__(256) void hist_rank_kernel(const int* __restrict__ dst,
                                                        unsigned short* __restrict__ rank16,
                                                        unsigned short* __restrict__ hist_g) {
    __shared__ unsigned int lh[NP / 2];        // 9500 u32 = 38 KB, 2 rows per word
    int c    = blockIdx.x;
    int tid  = threadIdx.x;
    for (int i = tid; i < NP / 2; i += 256) lh[i] = 0u;
    __syncthreads();
    int base = c * ECH;
    int end  = min(base + ECH, ESG);
    for (int e = base + tid; e < end; e += 256) {
        int d = __builtin_nontemporal_load(dst + e);
        unsigned sh  = (d & 1) << 4;
        unsigned old = atomicAdd(&lh[d >> 1], 1u << sh);
        __builtin_nontemporal_store((unsigned short)((old >> sh) & 0xffffu), rank16 + e);
    }
    __syncthreads();
    unsigned int* out = (unsigned int*)(hist_g + (size_t)c * NP);
    for (int i = tid; i < NP / 2; i += 256) out[i] = lh[i];
}

// ---------------------------------------------------------------- pass 2: per-row prefix over chunks
__global__ __launch_bounds__(256) void prefix_kernel(unsigned short* __restrict__ hist_g,
                                                     int* __restrict__ deg) {
    int r = blockIdx.x * 256 + threadIdx.x;
    if (r >= NP) return;
    unsigned run = 0;
    for (int c = 0; c < NCH; c++) {
        size_t idx = (size_t)c * NP + r;
        unsigned t = hist_g[idx];
        hist_g[idx] = (unsigned short)run;
        run += t;
    }
    deg[r] = (int)run;
}

// single-block exclusive scan of degree -> row_ptr; computes dinv
__global__ void scan_kernel(const int* __restrict__ deg, int* __restrict__ row_ptr,
                            float* __restrict__ dinv) {
    const int T = 256;
    const int PER = (NP + T - 1) / T;   // 75
    __shared__ int totals[T];
    __shared__ int excl[T + 1];
    int t = threadIdx.x;
    int base = t * PER;
    int local = 0;
    for (int i = 0; i < PER; i++) {
        int idx = base + i;
        if (idx < NP) local += deg[idx];
    }
    totals[t] = local;
    __syncthreads();
    if (t == 0) {
        int r = 0;
        for (int i = 0; i < T; i++) { excl[i] = r; r += totals[i]; }
        excl[T] = r;
    }
    __syncthreads();
    int run = excl[t];
    for (int i = 0; i < PER; i++) {
        int idx = base + i;
        if (idx < NP) {
            int dg = deg[idx];
            row_ptr[idx] = run;
            dinv[idx]    = 1.0f / sqrtf((float)dg + 1.0f);
            run += dg;
        }
    }
    if (t == 0) row_ptr[NP] = excl[T];
}

// ---------------------------------------------------------------- W1+W2 split + drug_ptr table (single launch)
__global__ __launch_bounds__(256) void wsplit2_kernel(const float* __restrict__ W1,
                                                      const float* __restrict__ W2,
                                                      unsigned short* __restrict__ B1h,
                                                      unsigned short* __restrict__ B1l,
                                                      unsigned short* __restrict__ B2h,
                                                      unsigned short* __restrict__ B2l,
                                                      const int* __restrict__ sg_idx,
                                                      int* __restrict__ drug_ptr) {
    int b = blockIdx.x;
    if (b >= 2 * CHN) {                      // drug_ptr tail blocks
        int d = (b - 2 * CHN) * 256 + threadIdx.x;
        if (d <= ND) drug_ptr[d] = lower_bound_dev(sg_idx, NSG, d);
        return;
    }
    int which = b >> 8;
    int c = b & 255;             // output row = W column
    int k = threadIdx.x;         // 256
    const float* W = which ? W2 : W1;
    unsigned short* Bh = which ? B2h : B1h;
    unsigned short* Bl = which ? B2l : B1l;
    float v = W[(size_t)k * 256 + c];
    unsigned short h = f2bf(v);
    Bh[(size_t)c * 256 + k] = h;
    Bl[(size_t)c * 256 + k] = f2bf(v - bf2f(h));
}

// ---------------------------------------------------------------- GEMM block swizzle (XCD-affine)
static __device__ __forceinline__ bool gemm_map(int g, int& bx, int& by) {
    int xcd = g & 7, j = g >> 3;
    by = j & 3;
    bx = ((j >> 2) << 3) | xcd;
    return bx < GEMM_BX;
}

// ---------------------------------------------------------------- MFMA GEMM body
// Cb[M,256] = bf16( (A[M,256] @ B[256,256]) * dinv[row] ) via 3-term bf16 split.
static __device__ __forceinline__ void mfma_gemm_body(const float* __restrict__ A,
                                                      const unsigned short* __restrict__ Bth,
                                                      const unsigned short* __restrict__ Btl,
                                                      const float* __restrict__ dinv,
                                                      unsigned short* __restrict__ Cb,
                                                      int M, int bx, int by) {
    __shared__ bf16x8 U[4][256];       // 0:Ah 1:Al 2:Bh 3:Bl ; 16 KB
    int tid = threadIdx.x;
    int l  = tid & 63, w = tid >> 6;
    int wm = w >> 1,  wn = w & 1;
    int m0 = bx * 64, n0 = by * 64;
    int sr = tid >> 2, sq = tid & 3;
    int arow = m0 + sr;
    int brow = n0 + sr;
    bool aok = (arow < M);
    const float*  gA  = A + (size_t)arow * 256;
    const bf16x8* gBh = (const bf16x8*)Bth + (size_t)brow * 32;
    const bf16x8* gBl = (const bf16x8*)Btl + (size_t)brow * 32;
    int swz_w = (sq << 6) + (sr ^ (sq << 1));       // swizzled write unit
    int qa = l >> 4;
    int ra = wm * 32 + (l & 15);
    int rb = wn * 32 + (l & 15);
    int fra = (qa << 6) + (ra ^ (qa << 1));         // swizzled A-frag unit
    int frb = (qa << 6) + (rb ^ (qa << 1));         // swizzled B-frag unit
    f32x4 acc[2][2] = {};
    for (int ku = 0; ku < 32; ku += 4) {            // 8 K-steps of 32
        float4 v0 = make_float4(0.f, 0.f, 0.f, 0.f), v1 = v0;
        if (aok) {
            v0 = *(const float4*)(gA + (ku + sq) * 8);
            v1 = *(const float4*)(gA + (ku + sq) * 8 + 4);
        }
        bf16x8 vc = gBh[ku + sq];
        bf16x8 vd = gBl[ku + sq];
        bf16x8 va, vb;
        cvt8(v0, v1, va, vb);
        __syncthreads();                            // prev-iter reads done
        U[0][swz_w] = va;
        U[1][swz_w] = vb;
        U[2][swz_w] = vc;
        U[3][swz_w] = vd;
        __syncthreads();
        bf16x8 ah0 = U[0][fra], ah1 = U[0][fra + 16];
        bf16x8 al0 = U[1][fra], al1 = U[1][fra + 16];
        bf16x8 bh0 = U[2][frb], bh1 = U[2][frb + 16];
        bf16x8 bl0 = U[3][frb], bl1 = U[3][frb + 16];
        acc[0][0] = __builtin_amdgcn_mfma_f32_16x16x32_bf16(ah0, bh0, acc[0][0], 0, 0, 0);
        acc[0][1] = __builtin_amdgcn_mfma_f32_16x16x32_bf16(ah0, bh1, acc[0][1], 0, 0, 0);
        acc[1][0] = __builtin_amdgcn_mfma_f32_16x16x32_bf16(ah1, bh0, acc[1][0], 0, 0, 0);
        acc[1][1] = __builtin_amdgcn_mfma_f32_16x16x32_bf16(ah1, bh1, acc[1][1], 0, 0, 0);
        acc[0][0] = __builtin_amdgcn_mfma_f32_16x16x32_bf16(ah0, bl0, acc[0][0], 0, 0, 0);
        acc[0][1] = __builtin_amdgcn_mfma_f32_16x16x32_bf16(ah0, bl1, acc[0][1], 0, 0, 0);
        acc[1][0] = __builtin_amdgcn_mfma_f32_16x16x32_bf16(ah1, bl0, acc[1][0], 0, 0, 0);
        acc[1][1] = __builtin_amdgcn_mfma_f32_16x16x32_bf16(ah1, bl1, acc[1][1], 0, 0, 0);
        acc[0][0] = __builtin_amdgcn_mfma_f32_16x16x32_bf16(al0, bh0, acc[0][0], 0, 0, 0);
        acc[0][1] = __builtin_amdgcn_mfma_f32_16x16x32_bf16(al0, bh1, acc[0][1], 0, 0, 0);
        acc[1][0] = __builtin_amdgcn_mfma_f32_16x16x32_bf16(al1, bh0, acc[1][0], 0, 0, 0);
        acc[1][1] = __builtin_amdgcn_mfma_f32_16x16x32_bf16(al1, bh1, acc[1][1], 0, 0, 0);
    }
#pragma unroll
    for (int mi = 0; mi < 2; mi++) {
#pragma unroll
        for (int j = 0; j < 4; j++) {
            int row = m0 + wm * 32 + mi * 16 + (l >> 4) * 4 + j;
            if (row < M) {
                float dv = dinv[row];
                size_t o = (size_t)row * 256 + n0 + wn * 32 + (l & 15);
                Cb[o]      = f2bf(acc[mi][0][j] * dv);
                Cb[o + 16] = f2bf(acc[mi][1][j] * dv);
            }
        }
    }
}

// ---------------------------------------------------------------- plain mfma gemm (layer 2), swizzled 1-D grid
__global__ __launch_bounds__(256) void gemm_kernel(const float* __restrict__ A,
                                                   const unsigned short* __restrict__ Bth,
                                                   const unsigned short* __restrict__ Btl,
                                                   const float* __restrict__ dinv,
                                                   unsigned short* __restrict__ Cb,
                                                   int M) {
    int bx, by;
    if (!gemm_map(blockIdx.x, bx, by)) return;
    mfma_gemm_body(A, Bth, Btl, dinv, Cb, M, bx, by);
}

// ---------------------------------------------------------------- fused fill + mfma gemm1
// Fill-side streaming loads (src/dst/rank16) and the csr scatter store are
// non-temporal: they are touch-once and must not evict the gemm's x panels.
__global__ __launch_bounds__(256) void fill_gemm_kernel(const int* __restrict__ src,
                                                        const int* __restrict__ dst,
                                                        const int* __restrict__ row_ptr,
                                                        const unsigned short* __restrict__ choff,
                                                        const unsigned short* __restrict__ rank16,
                                                        unsigned short* __restrict__ csr_srcu,
                                                        const float* __restrict__ A,
                                                        const unsigned short* __restrict__ Bth,
                                                        const unsigned short* __restrict__ Btl,
                                                        const float* __restrict__ dinv,
                                                        unsigned short* __restrict__ Cb) {
    if (blockIdx.x < GEMM_SW_BLK) {
        int bx, by;
        if (!gemm_map(blockIdx.x, bx, by)) return;
        mfma_gemm_body(A, Bth, Btl, dinv, Cb, NP, bx, by);
        return;
    }
    int e = (blockIdx.x - GEMM_SW_BLK) * 256 + threadIdx.x;
    if (e >= ESG) return;
    int s = __builtin_nontemporal_load(src + e);
    int d = __builtin_nontemporal_load(dst + e);
    int r = (int)__builtin_nontemporal_load(rank16 + e);
    int c = e / ECH;
    int pos = row_ptr[d] + (int)choff[(size_t)c * NP + d] + r;
    __builtin_nontemporal_store((unsigned short)s, csr_srcu + pos);
}

// ---------------------------------------------------------------- SpMM, XCD-sliced, direct-indexed gathers
// Wave = one (row, slice). Lanes: g = lane>>3 (8 edges/iter), l = lane&7.
// Main loop unmasked, unroll 4 (TLP beats ILP -- round-7/8 A/B).
// csr index loads NON-TEMPORAL: the 3 MB/XCD index stream must not evict the
// 2.43 MB/XCD hwbf gather table from L2 (round-10 theory: gather latency
// ~600cy under load = partial L2 thrash by the index stream).
__global__ __launch_bounds__(256) void spmm_kernel(const unsigned short* __restrict__ hwbf,
                                                   const int* __restrict__ row_ptr,
                                                   const unsigned short* __restrict__ csr_srcu,
                                                   const float* __restrict__ dinv,
                                                   const float* __restrict__ bias,
                                                   const float* __restrict__ residual,
                                                   float* __restrict__ outf,
                                                   unsigned short* __restrict__ outbf,
                                                   int do_relu) {
    int b     = blockIdx.x;
    int slice = b & 3;
    int quad  = b >> 2;                        // 0 .. NP/4-1
    int wv    = threadIdx.x >> 6;
    int lane  = threadIdx.x & 63;
    int g     = lane >> 3;                     // edge group 0..7
    int l     = lane & 7;                      // channel octet within slice
    int row   = quad * 4 + wv;                 // < NP
    int c     = slice * 64 + (l << 3);
    int cb    = c << 1;                        // byte offset of channel octet
    int lo = __builtin_amdgcn_readfirstlane(row_ptr[row]);
    int hi = __builtin_amdgcn_readfirstlane(row_ptr[row + 1]);
    size_t o = (size_t)row * 256 + c;
    // early epilogue prefetch (only the 8 lanes that will write)
    u16x8 sv = {};
    float4 bv0, bv1, rv0, rv1;
    float dvr = 0.f;
    if (g == 0) {
        sv  = *(const u16x8*)(hwbf + o);       // own prescaled bf16 slice (self)
        bv0 = *(const float4*)(bias + c);
        bv1 = *(const float4*)(bias + c + 4);
        if (residual) {
            rv0 = *(const float4*)(residual + o);
            rv1 = *(const float4*)(residual + o + 4);
        }
        dvr = dinv[row];
    }
    f32x2 a2[4] = {};
    const char* hb = (const char*)hwbf;
    int deg   = hi - lo;
    int kfull = deg >> 3;                      // unmasked iterations
#pragma unroll 4
    for (int k = 0; k < kfull; k++) {
        int e   = lo + (k << 3) + g;
        int off = ((int)__builtin_nontemporal_load(csr_srcu + e) << 9) + cb;
        uint4 w = *(const uint4*)(hb + off);
        a2[0] += bfpair(w.x);
        a2[1] += bfpair(w.y);
        a2[2] += bfpair(w.z);
        a2[3] += bfpair(w.w);
    }
    int rem = deg & 7;
    if (rem) {
        int e   = lo + (kfull << 3) + g;
        float m = (g < rem) ? 1.f : 0.f;
        int ee  = (g < rem) ? e : (hi - 1);    // safe (rem>0 => hi>lo)
        int off = ((int)__builtin_nontemporal_load(csr_srcu + ee) << 9) + cb;
        uint4 w = *(const uint4*)(hb + off);
        f32x2 m2; m2.x = m; m2.y = m;
        a2[0] += m2 * bfpair(w.x);
        a2[1] += m2 * bfpair(w.y);
        a2[2] += m2 * bfpair(w.z);
        a2[3] += m2 * bfpair(w.w);
    }
    float a[8] = {a2[0].x, a2[0].y, a2[1].x, a2[1].y, a2[2].x, a2[2].y, a2[3].x, a2[3].y};
    // combine the 8 edge-groups (same channels, different edges)
#pragma unroll
    for (int i = 0; i < 8; i++) {
        a[i] += __shfl_xor(a[i], 8);
        a[i] += __shfl_xor(a[i], 16);
        a[i] += __shfl_xor(a[i], 32);
    }
    if (g == 0) {
        float r[8];
        float bb[8] = {bv0.x, bv0.y, bv0.z, bv0.w, bv1.x, bv1.y, bv1.z, bv1.w};
#pragma unroll
        for (int i = 0; i < 8; i++)
            r[i] = (a[i] + bf2f((unsigned short)sv[i])) * dvr + bb[i];
        if (residual) {
            r[0] += rv0.x; r[1] += rv0.y; r[2] += rv0.z; r[3] += rv0.w;
            r[4] += rv1.x; r[5] += rv1.y; r[6] += rv1.z; r[7] += rv1.w;
        }
        if (do_relu) {
#pragma unroll
            for (int i = 0; i < 8; i++) r[i] = fmaxf(r[i], 0.f);
        }
        if (outf) {
            *(float4*)(outf + o)     = make_float4(r[0], r[1], r[2], r[3]);
            *(float4*)(outf + o + 4) = make_float4(r[4], r[5], r[6], r[7]);
        }
        if (outbf) {
            u16x8 ob;
#pragma unroll
            for (int i = 0; i < 8; i++) ob[i] = f2bf(r[i]);
            *(u16x8*)(outbf + o) = ob;
        }
    }
}

// ---------------------------------------------------------------- pooling, XCD-sliced, direct-indexed
// sg_nodes index stream non-temporal (protects the h2bf gather table in L2).
__global__ __launch_bounds__(256) void pool_kernel(const unsigned short* __restrict__ h2bf,
                                                   const int* __restrict__ sg_nodes,
                                                   const int* __restrict__ drug_ptr,
                                                   float* __restrict__ drug_emb) {
    int b     = blockIdx.x;
    int slice = b & 3;
    int d     = b >> 2;                        // < ND
    int wv    = threadIdx.x >> 6;
    int lane  = threadIdx.x & 63;
    int g     = lane >> 3;                     // node group 0..7
    int l     = lane & 7;                      // channel octet
    int c     = slice * 64 + (l << 3);
    int cb    = c << 1;
    __shared__ float s_red[4][64];
    int lo0 = __builtin_amdgcn_readfirstlane(drug_ptr[d]);
    int hi0 = __builtin_amdgcn_readfirstlane(drug_ptr[d + 1]);
    int len = hi0 - lo0;
    int lo = __builtin_amdgcn_readfirstlane(lo0 + (int)(((long long)len * wv) / 4));
    int hi = __builtin_amdgcn_readfirstlane(lo0 + (int)(((long long)len * (wv + 1)) / 4));
    f32x2 a2[4] = {};
    const char* hb = (const char*)h2bf;
    int deg   = hi - lo;
    int kfull = deg >> 3;
#pragma unroll 4
    for (int k = 0; k < kfull; k++) {
        int e   = lo + (k << 3) + g;
        int off = (__builtin_nontemporal_load(sg_nodes + e) << 9) + cb;
        uint4 w = *(const uint4*)(hb + off);
        a2[0] += bfpair(w.x);
        a2[1] += bfpair(w.y);
        a2[2] += bfpair(w.z);
        a2[3] += bfpair(w.w);
    }
    int rem = deg & 7;
    if (rem) {
        int e   = lo + (kfull << 3) + g;
        float m = (g < rem) ? 1.f : 0.f;
        int ee  = (g < rem) ? e : (hi - 1);
        int off = (__builtin_nontemporal_load(sg_nodes + ee) << 9) + cb;
        uint4 w = *(const uint4*)(hb + off);
        f32x2 m2; m2.x = m; m2.y = m;
        a2[0] += m2 * bfpair(w.x);
        a2[1] += m2 * bfpair(w.y);
        a2[2] += m2 * bfpair(w.z);
        a2[3] += m2 * bfpair(w.w);
    }
    float a[8] = {a2[0].x, a2[0].y, a2[1].x, a2[1].y, a2[2].x, a2[2].y, a2[3].x, a2[3].y};
#pragma unroll
    for (int i = 0; i < 8; i++) {
        a[i] += __shfl_xor(a[i], 8);
        a[i] += __shfl_xor(a[i], 16);
        a[i] += __shfl_xor(a[i], 32);
    }
    if (g == 0) {
        *(float4*)&s_red[wv][l << 3]       = make_float4(a[0], a[1], a[2], a[3]);
        *(float4*)&s_red[wv][(l << 3) + 4] = make_float4(a[4], a[5], a[6], a[7]);
    }
    __syncthreads();
    if (threadIdx.x < 64) {
        int t = threadIdx.x;
        float inv = 1.0f / (float)max(len, 1);
        float r = (s_red[0][t] + s_red[1][t]) + (s_red[2][t] + s_red[3][t]);
        drug_emb[(size_t)d * 256 + slice * 64 + t] = r * inv;
    }
}

// ---------------------------------------------------------------- dot head (wave per pair)
__global__ __launch_bounds__(256) void dot_kernel(const float* __restrict__ drug_emb,
                                                  const int* __restrict__ ddb,
                                                  float* __restrict__ out) {
    int wave = threadIdx.x >> 6;
    int lane = threadIdx.x & 63;
    int p = blockIdx.x * 4 + wave;
    if (p >= BDD) return;
    int a = ddb[p];
    int b = ddb[BDD + p];
    const float4* ea = (const float4*)(drug_emb + (size_t)a * 256);
    const float4* eb = (const float4*)(drug_emb + (size_t)b * 256);
    float4 va = ea[lane];
    float4 vb = eb[lane];
    float s = va.x * vb.x + va.y * vb.y + va.z * vb.z + va.w * vb.w;
#pragma unroll
    for (int off = 32; off > 0; off >>= 1) s += __shfl_down(s, off, 64);
    if (lane == 0) out[p] = s;
}

// ---------------------------------------------------------------- launcher
extern "C" void kernel_launch(void* const* d_in, const int* in_sizes, int n_in,
                              void* d_out, int out_size, void* d_ws, size_t ws_size,
                              hipStream_t stream) {
    const float* x        = (const float*)d_in[0];
    const int*   ddb      = (const int*)d_in[1];
    // d_in[2] edge_attr, d_in[3] edge_cell_lines: unused by reference
    const int*   sg_edge  = (const int*)d_in[4];   // [2, ESG]: src then dst
    const int*   sg_nodes = (const int*)d_in[5];
    const int*   sg_idx   = (const int*)d_in[6];
    const float* W1       = (const float*)d_in[7];
    const float* b1       = (const float*)d_in[8];
    const float* W2       = (const float*)d_in[9];
    const float* b2       = (const float*)d_in[10];
    float* out = (float*)d_out;

    char* ws = (char*)d_ws;
    size_t off = 0;
    auto alloc = [&](size_t bytes) -> void* {
        void* p = ws + off;
        off = (off + bytes + 255) & ~(size_t)255;
        return p;
    };
    int*   deg      = (int*)alloc(NP * sizeof(int));
    float* dinv     = (float*)alloc(NP * sizeof(float));
    int*   row_ptr  = (int*)alloc((NP + 1) * sizeof(int));
    int*   drug_ptr = (int*)alloc((ND + 1) * sizeof(int));
    unsigned short* rank16   = (unsigned short*)alloc((size_t)ESG * sizeof(unsigned short));
    unsigned short* hist_g   = (unsigned short*)alloc((size_t)NCH * NP * sizeof(unsigned short));
    unsigned short* csr_srcu = (unsigned short*)alloc((size_t)ESG * sizeof(unsigned short));
    unsigned short* bufAbf = (unsigned short*)alloc((size_t)NP * CHN * 2);        // bf16 hw twin (prescaled)
    float* h1       = (float*)alloc((size_t)NP * CHN * sizeof(float));
    unsigned short* h2bf   = (unsigned short*)alloc((size_t)NP * CHN * 2);
    float* drug_emb = (float*)alloc((size_t)ND * CHN * sizeof(float));
    unsigned short* bt1h = (unsigned short*)alloc((size_t)CHN * CHN * 2);
    unsigned short* bt1l = (unsigned short*)alloc((size_t)CHN * CHN * 2);
    unsigned short* bt2h = (unsigned short*)alloc((size_t)CHN * CHN * 2);
    unsigned short* bt2l = (unsigned short*)alloc((size_t)CHN * CHN * 2);

    const int* src = sg_edge;
    const int* dst = sg_edge + ESG;

    // counting-sort CSR build (LDS atomics only) + degree/row_ptr/dinv
    hist_rank_kernel<<<NCH, 256, 0, stream>>>(dst, rank16, hist_g);
    prefix_kernel<<<(NP + 255) / 256, 256, 0, stream>>>(hist_g, deg);
    scan_kernel<<<1, 256, 0, stream>>>(deg, row_ptr, dinv);

    // weight splits + drug_ptr table (single launch)
    wsplit2_kernel<<<2 * CHN + DP_BLKS, 256, 0, stream>>>(W1, W2, bt1h, bt1l,
                                                          bt2h, bt2l, sg_idx, drug_ptr);

    // fused: atomic-free CSR fill + MFMA gemm1 (A = x fp32, split in-register;
    // XCD-affine swizzled gemm blocks; bf16-only output)
    fill_gemm_kernel<<<GEMM_SW_BLK + FILL_BLK, 256, 0, stream>>>(src, dst, row_ptr,
                                                                 hist_g, rank16, csr_srcu,
                                                                 x, bt1h, bt1l,
                                                                 dinv, bufAbf);
    // layer 1: h1 = relu(agg + self + b1)   [self from bufAbf, bf16]
    spmm_kernel<<<NP, 256, 0, stream>>>(bufAbf, row_ptr, csr_srcu, dinv, b1,
                                        nullptr, h1, nullptr, 1);
    // layer 2: bufAbf = bf16(h1 @ W2 * dinv); h2bf = agg + self + b2 + h1
    gemm_kernel<<<GEMM_SW_BLK, 256, 0, stream>>>(h1, bt2h, bt2l, dinv,
                                                 bufAbf, NP);
    spmm_kernel<<<NP, 256, 0, stream>>>(bufAbf, row_ptr, csr_srcu, dinv, b2,
                                        h1, nullptr, h2bf, 0);
    // scatter-mean pooling (XCD-sliced, direct-indexed, drug_ptr table)
    pool_kernel<<<ND * 4, 256, 0, stream>>>(h2bf, sg_nodes, drug_ptr, drug_emb);
    // dot-product head
    dot_kernel<<<(BDD + 3) / 4, 256, 0, stream>>>(drug_emb, ddb, out);
}

// Round 11
// 352.210 us; speedup vs baseline: 1.1787x; 1.1787x over previous
//
#include <hip/hip_runtime.h>
#include <hip/hip_bf16.h>
#include <math.h>

#define NP   19000      // NUM_PROTEINS
#define ND   1024       // NUM_DRUGS
#define CHN  256        // IN_CH == EMBED
#define ESG  1500000    // E_SG
#define NSG  800000     // N_SG
#define BDD  4096       // B_DD

#define GEMM_BX   ((NP + 63) / 64)       // 297 row-panels
#define GEMM_SW_G ((GEMM_BX + 7) / 8)    // 38 groups of 8 panels (one per XCD)
#define GEMM_SW_BLK (GEMM_SW_G * 8 * 4)  // 1216 swizzled gemm blocks (28 dummies)
#define FILL_BLK  ((ESG + 255) / 256)    // 5860

#define NCH  256                          // edge chunks for counting sort
#define ECH  ((ESG + NCH - 1) / NCH)      // 5860 edges per chunk
#define DP_BLKS (((ND + 1) + 255) / 256)  // 5 drug_ptr blocks

typedef __attribute__((ext_vector_type(8))) short bf16x8;           // 8 bf16 = 4 VGPR
typedef __attribute__((ext_vector_type(8))) unsigned short u16x8;   // 16B gather
typedef __attribute__((ext_vector_type(4))) float f32x4;            // MFMA acc
typedef __attribute__((ext_vector_type(2))) float f32x2;            // packed-f32 pair

// ---------------------------------------------------------------- bf16 helpers (raw ushort)
static __device__ __forceinline__ unsigned short f2bf(float f) {
    unsigned u = __float_as_uint(f);
    u = u + 0x7fffu + ((u >> 16) & 1u);        // round-to-nearest-even
    return (unsigned short)(u >> 16);
}
static __device__ __forceinline__ float bf2f(unsigned short h) {
    return __uint_as_float((unsigned)h << 16);
}
// u32 of 2 bf16 -> f32 pair (ch 2j, 2j+1); feeds v_pk_add/v_pk_fma
static __device__ __forceinline__ f32x2 bfpair(unsigned w) {
    f32x2 r;
    r.x = __uint_as_float(w << 16);
    r.y = __uint_as_float(w & 0xffff0000u);
    return r;
}
// fp32x8 -> bf16 hi/lo split, in-register
static __device__ __forceinline__ void cvt8(float4 v0, float4 v1, bf16x8& h8, bf16x8& l8) {
    float vv[8] = {v0.x, v0.y, v0.z, v0.w, v1.x, v1.y, v1.z, v1.w};
#pragma unroll
    for (int i = 0; i < 8; i++) {
        unsigned short h = f2bf(vv[i]);
        h8[i] = (short)h;
        l8[i] = (short)f2bf(vv[i] - bf2f(h));
    }
}

// ---------------------------------------------------------------- utilities
static __device__ __forceinline__ int lower_bound_dev(const int* __restrict__ arr, int n, int val) {
    int lo = 0, hi = n;
    while (lo < hi) {
        int mid = (lo + hi) >> 1;
        if (arr[mid] < val) lo = mid + 1; else hi = mid;
    }
    return lo;
}

// ---------------------------------------------------------------- chunked counting sort, pass 1
// NOTE round-10 lesson: NO __builtin_nontemporal_* anywhere. On gfx950 "nt"
// BYPASSES L2 (not a priority hint) -> csr stream fell out of L2 and spmm
// regressed 59.6 -> 73.3 us. Plain cached accesses are correct here.
__global__ __launch_bounds__(256) void hist_rank_kernel(const int* __restrict__ dst,
                                                        unsigned short* __restrict__ rank16,
                                                        unsigned short* __restrict__ hist_g) {
    __shared__ unsigned int lh[NP / 2];        // 9500 u32 = 38 KB, 2 rows per word
    int c    = blockIdx.x;
    int tid  = threadIdx.x;
    for (int i = tid; i < NP / 2; i += 256) lh[i] = 0u;
    __syncthreads();
    int base = c * ECH;
    int end  = min(base + ECH, ESG);
    for (int e = base + tid; e < end; e += 256) {
        int d = dst[e];
        unsigned sh  = (d & 1) << 4;
        unsigned old = atomicAdd(&lh[d >> 1], 1u << sh);
        rank16[e] = (unsigned short)((old >> sh) & 0xffffu);
    }
    __syncthreads();
    unsigned int* out = (unsigned int*)(hist_g + (size_t)c * NP);
    for (int i = tid; i < NP / 2; i += 256) out[i] = lh[i];
}

// ---------------------------------------------------------------- pass 2: per-row prefix over chunks
__global__ __launch_bounds__(256) void prefix_kernel(unsigned short* __restrict__ hist_g,
                                                     int* __restrict__ deg) {
    int r = blockIdx.x * 256 + threadIdx.x;
    if (r >= NP) return;
    unsigned run = 0;
    for (int c = 0; c < NCH; c++) {
        size_t idx = (size_t)c * NP + r;
        unsigned t = hist_g[idx];
        hist_g[idx] = (unsigned short)run;
        run += t;
    }
    deg[r] = (int)run;
}

// single-block exclusive scan of degree -> row_ptr; computes dinv
__global__ void scan_kernel(const int* __restrict__ deg, int* __restrict__ row_ptr,
                            float* __restrict__ dinv) {
    const int T = 256;
    const int PER = (NP + T - 1) / T;   // 75
    __shared__ int totals[T];
    __shared__ int excl[T + 1];
    int t = threadIdx.x;
    int base = t * PER;
    int local = 0;
    for (int i = 0; i < PER; i++) {
        int idx = base + i;
        if (idx < NP) local += deg[idx];
    }
    totals[t] = local;
    __syncthreads();
    if (t == 0) {
        int r = 0;
        for (int i = 0; i < T; i++) { excl[i] = r; r += totals[i]; }
        excl[T] = r;
    }
    __syncthreads();
    int run = excl[t];
    for (int i = 0; i < PER; i++) {
        int idx = base + i;
        if (idx < NP) {
            int dg = deg[idx];
            row_ptr[idx] = run;
            dinv[idx]    = 1.0f / sqrtf((float)dg + 1.0f);
            run += dg;
        }
    }
    if (t == 0) row_ptr[NP] = excl[T];
}

// ---------------------------------------------------------------- W1+W2 split + drug_ptr table (single launch)
__global__ __launch_bounds__(256) void wsplit2_kernel(const float* __restrict__ W1,
                                                      const float* __restrict__ W2,
                                                      unsigned short* __restrict__ B1h,
                                                      unsigned short* __restrict__ B1l,
                                                      unsigned short* __restrict__ B2h,
                                                      unsigned short* __restrict__ B2l,
                                                      const int* __restrict__ sg_idx,
                                                      int* __restrict__ drug_ptr) {
    int b = blockIdx.x;
    if (b >= 2 * CHN) {                      // drug_ptr tail blocks
        int d = (b - 2 * CHN) * 256 + threadIdx.x;
        if (d <= ND) drug_ptr[d] = lower_bound_dev(sg_idx, NSG, d);
        return;
    }
    int which = b >> 8;
    int c = b & 255;             // output row = W column
    int k = threadIdx.x;         // 256
    const float* W = which ? W2 : W1;
    unsigned short* Bh = which ? B2h : B1h;
    unsigned short* Bl = which ? B2l : B1l;
    float v = W[(size_t)k * 256 + c];
    unsigned short h = f2bf(v);
    Bh[(size_t)c * 256 + k] = h;
    Bl[(size_t)c * 256 + k] = f2bf(v - bf2f(h));
}

// ---------------------------------------------------------------- GEMM block swizzle (XCD-affine)
static __device__ __forceinline__ bool gemm_map(int g, int& bx, int& by) {
    int xcd = g & 7, j = g >> 3;
    by = j & 3;
    bx = ((j >> 2) << 3) | xcd;
    return bx < GEMM_BX;
}

// ---------------------------------------------------------------- MFMA GEMM body
// Cb[M,256] = bf16( (A[M,256] @ B[256,256]) * dinv[row] ) via 3-term bf16 split.
static __device__ __forceinline__ void mfma_gemm_body(const float* __restrict__ A,
                                                      const unsigned short* __restrict__ Bth,
                                                      const unsigned short* __restrict__ Btl,
                                                      const float* __restrict__ dinv,
                                                      unsigned short* __restrict__ Cb,
                                                      int M, int bx, int by) {
    __shared__ bf16x8 U[4][256];       // 0:Ah 1:Al 2:Bh 3:Bl ; 16 KB
    int tid = threadIdx.x;
    int l  = tid & 63, w = tid >> 6;
    int wm = w >> 1,  wn = w & 1;
    int m0 = bx * 64, n0 = by * 64;
    int sr = tid >> 2, sq = tid & 3;
    int arow = m0 + sr;
    int brow = n0 + sr;
    bool aok = (arow < M);
    const float*  gA  = A + (size_t)arow * 256;
    const bf16x8* gBh = (const bf16x8*)Bth + (size_t)brow * 32;
    const bf16x8* gBl = (const bf16x8*)Btl + (size_t)brow * 32;
    int swz_w = (sq << 6) + (sr ^ (sq << 1));       // swizzled write unit
    int qa = l >> 4;
    int ra = wm * 32 + (l & 15);
    int rb = wn * 32 + (l & 15);
    int fra = (qa << 6) + (ra ^ (qa << 1));         // swizzled A-frag unit
    int frb = (qa << 6) + (rb ^ (qa << 1));         // swizzled B-frag unit
    f32x4 acc[2][2] = {};
    for (int ku = 0; ku < 32; ku += 4) {            // 8 K-steps of 32
        float4 v0 = make_float4(0.f, 0.f, 0.f, 0.f), v1 = v0;
        if (aok) {
            v0 = *(const float4*)(gA + (ku + sq) * 8);
            v1 = *(const float4*)(gA + (ku + sq) * 8 + 4);
        }
        bf16x8 vc = gBh[ku + sq];
        bf16x8 vd = gBl[ku + sq];
        bf16x8 va, vb;
        cvt8(v0, v1, va, vb);
        __syncthreads();                            // prev-iter reads done
        U[0][swz_w] = va;
        U[1][swz_w] = vb;
        U[2][swz_w] = vc;
        U[3][swz_w] = vd;
        __syncthreads();
        bf16x8 ah0 = U[0][fra], ah1 = U[0][fra + 16];
        bf16x8 al0 = U[1][fra], al1 = U[1][fra + 16];
        bf16x8 bh0 = U[2][frb], bh1 = U[2][frb + 16];
        bf16x8 bl0 = U[3][frb], bl1 = U[3][frb + 16];
        acc[0][0] = __builtin_amdgcn_mfma_f32_16x16x32_bf16(ah0, bh0, acc[0][0], 0, 0, 0);
        acc[0][1] = __builtin_amdgcn_mfma_f32_16x16x32_bf16(ah0, bh1, acc[0][1], 0, 0, 0);
        acc[1][0] = __builtin_amdgcn_mfma_f32_16x16x32_bf16(ah1, bh0, acc[1][0], 0, 0, 0);
        acc[1][1] = __builtin_amdgcn_mfma_f32_16x16x32_bf16(ah1, bh1, acc[1][1], 0, 0, 0);
        acc[0][0] = __builtin_amdgcn_mfma_f32_16x16x32_bf16(ah0, bl0, acc[0][0], 0, 0, 0);
        acc[0][1] = __builtin_amdgcn_mfma_f32_16x16x32_bf16(ah0, bl1, acc[0][1], 0, 0, 0);
        acc[1][0] = __builtin_amdgcn_mfma_f32_16x16x32_bf16(ah1, bl0, acc[1][0], 0, 0, 0);
        acc[1][1] = __builtin_amdgcn_mfma_f32_16x16x32_bf16(ah1, bl1, acc[1][1], 0, 0, 0);
        acc[0][0] = __builtin_amdgcn_mfma_f32_16x16x32_bf16(al0, bh0, acc[0][0], 0, 0, 0);
        acc[0][1] = __builtin_amdgcn_mfma_f32_16x16x32_bf16(al0, bh1, acc[0][1], 0, 0, 0);
        acc[1][0] = __builtin_amdgcn_mfma_f32_16x16x32_bf16(al1, bh0, acc[1][0], 0, 0, 0);
        acc[1][1] = __builtin_amdgcn_mfma_f32_16x16x32_bf16(al1, bh1, acc[1][1], 0, 0, 0);
    }
#pragma unroll
    for (int mi = 0; mi < 2; mi++) {
#pragma unroll
        for (int j = 0; j < 4; j++) {
            int row = m0 + wm * 32 + mi * 16 + (l >> 4) * 4 + j;
            if (row < M) {
                float dv = dinv[row];
                size_t o = (size_t)row * 256 + n0 + wn * 32 + (l & 15);
                Cb[o]      = f2bf(acc[mi][0][j] * dv);
                Cb[o + 16] = f2bf(acc[mi][1][j] * dv);
            }
        }
    }
}

// ---------------------------------------------------------------- plain mfma gemm (layer 2), swizzled 1-D grid
__global__ __launch_bounds__(256) void gemm_kernel(const float* __restrict__ A,
                                                   const unsigned short* __restrict__ Bth,
                                                   const unsigned short* __restrict__ Btl,
                                                   const float* __restrict__ dinv,
                                                   unsigned short* __restrict__ Cb,
                                                   int M) {
    int bx, by;
    if (!gemm_map(blockIdx.x, bx, by)) return;
    mfma_gemm_body(A, Bth, Btl, dinv, Cb, M, bx, by);
}

// ---------------------------------------------------------------- fused fill + mfma gemm1
__global__ __launch_bounds__(256) void fill_gemm_kernel(const int* __restrict__ src,
                                                        const int* __restrict__ dst,
                                                        const int* __restrict__ row_ptr,
                                                        const unsigned short* __restrict__ choff,
                                                        const unsigned short* __restrict__ rank16,
                                                        unsigned short* __restrict__ csr_srcu,
                                                        const float* __restrict__ A,
                                                        const unsigned short* __restrict__ Bth,
                                                        const unsigned short* __restrict__ Btl,
                                                        const float* __restrict__ dinv,
                                                        unsigned short* __restrict__ Cb) {
    if (blockIdx.x < GEMM_SW_BLK) {
        int bx, by;
        if (!gemm_map(blockIdx.x, bx, by)) return;
        mfma_gemm_body(A, Bth, Btl, dinv, Cb, NP, bx, by);
        return;
    }
    int e = (blockIdx.x - GEMM_SW_BLK) * 256 + threadIdx.x;
    if (e >= ESG) return;
    int s = src[e], d = dst[e];
    int c = e / ECH;
    int pos = row_ptr[d] + (int)choff[(size_t)c * NP + d] + (int)rank16[e];
    csr_srcu[pos] = (unsigned short)s;
}

// ---------------------------------------------------------------- SpMM, XCD-sliced, direct-indexed gathers
// Wave = one (row, slice). Lanes: g = lane>>3 (8 edges/iter), l = lane&7.
// Main loop unmasked, unroll 4 (TLP beats ILP -- round-7/8 A/B).
// Plain cached loads everywhere (round-10: nt bypasses L2 on gfx950 -> -23%).
__global__ __launch_bounds__(256) void spmm_kernel(const unsigned short* __restrict__ hwbf,
                                                   const int* __restrict__ row_ptr,
                                                   const unsigned short* __restrict__ csr_srcu,
                                                   const float* __restrict__ dinv,
                                                   const float* __restrict__ bias,
                                                   const float* __restrict__ residual,
                                                   float* __restrict__ outf,
                                                   unsigned short* __restrict__ outbf,
                                                   int do_relu) {
    int b     = blockIdx.x;
    int slice = b & 3;
    int quad  = b >> 2;                        // 0 .. NP/4-1
    int wv    = threadIdx.x >> 6;
    int lane  = threadIdx.x & 63;
    int g     = lane >> 3;                     // edge group 0..7
    int l     = lane & 7;                      // channel octet within slice
    int row   = quad * 4 + wv;                 // < NP
    int c     = slice * 64 + (l << 3);
    int cb    = c << 1;                        // byte offset of channel octet
    int lo = __builtin_amdgcn_readfirstlane(row_ptr[row]);
    int hi = __builtin_amdgcn_readfirstlane(row_ptr[row + 1]);
    size_t o = (size_t)row * 256 + c;
    // early epilogue prefetch (only the 8 lanes that will write)
    u16x8 sv = {};
    float4 bv0, bv1, rv0, rv1;
    float dvr = 0.f;
    if (g == 0) {
        sv  = *(const u16x8*)(hwbf + o);       // own prescaled bf16 slice (self)
        bv0 = *(const float4*)(bias + c);
        bv1 = *(const float4*)(bias + c + 4);
        if (residual) {
            rv0 = *(const float4*)(residual + o);
            rv1 = *(const float4*)(residual + o + 4);
        }
        dvr = dinv[row];
    }
    f32x2 a2[4] = {};
    const char* hb = (const char*)hwbf;
    int deg   = hi - lo;
    int kfull = deg >> 3;                      // unmasked iterations
#pragma unroll 4
    for (int k = 0; k < kfull; k++) {
        int e   = lo + (k << 3) + g;
        int off = ((int)csr_srcu[e] << 9) + cb;
        uint4 w = *(const uint4*)(hb + off);
        a2[0] += bfpair(w.x);
        a2[1] += bfpair(w.y);
        a2[2] += bfpair(w.z);
        a2[3] += bfpair(w.w);
    }
    int rem = deg & 7;
    if (rem) {
        int e   = lo + (kfull << 3) + g;
        float m = (g < rem) ? 1.f : 0.f;
        int ee  = (g < rem) ? e : (hi - 1);    // safe (rem>0 => hi>lo)
        int off = ((int)csr_srcu[ee] << 9) + cb;
        uint4 w = *(const uint4*)(hb + off);
        f32x2 m2; m2.x = m; m2.y = m;
        a2[0] += m2 * bfpair(w.x);
        a2[1] += m2 * bfpair(w.y);
        a2[2] += m2 * bfpair(w.z);
        a2[3] += m2 * bfpair(w.w);
    }
    float a[8] = {a2[0].x, a2[0].y, a2[1].x, a2[1].y, a2[2].x, a2[2].y, a2[3].x, a2[3].y};
    // combine the 8 edge-groups (same channels, different edges)
#pragma unroll
    for (int i = 0; i < 8; i++) {
        a[i] += __shfl_xor(a[i], 8);
        a[i] += __shfl_xor(a[i], 16);
        a[i] += __shfl_xor(a[i], 32);
    }
    if (g == 0) {
        float r[8];
        float bb[8] = {bv0.x, bv0.y, bv0.z, bv0.w, bv1.x, bv1.y, bv1.z, bv1.w};
#pragma unroll
        for (int i = 0; i < 8; i++)
            r[i] = (a[i] + bf2f((unsigned short)sv[i])) * dvr + bb[i];
        if (residual) {
            r[0] += rv0.x; r[1] += rv0.y; r[2] += rv0.z; r[3] += rv0.w;
            r[4] += rv1.x; r[5] += rv1.y; r[6] += rv1.z; r[7] += rv1.w;
        }
        if (do_relu) {
#pragma unroll
            for (int i = 0; i < 8; i++) r[i] = fmaxf(r[i], 0.f);
        }
        if (outf) {
            *(float4*)(outf + o)     = make_float4(r[0], r[1], r[2], r[3]);
            *(float4*)(outf + o + 4) = make_float4(r[4], r[5], r[6], r[7]);
        }
        if (outbf) {
            u16x8 ob;
#pragma unroll
            for (int i = 0; i < 8; i++) ob[i] = f2bf(r[i]);
            *(u16x8*)(outbf + o) = ob;
        }
    }
}

// ---------------------------------------------------------------- pooling, XCD-sliced, direct-indexed
__global__ __launch_bounds__(256) void pool_kernel(const unsigned short* __restrict__ h2bf,
                                                   const int* __restrict__ sg_nodes,
                                                   const int* __restrict__ drug_ptr,
                                                   float* __restrict__ drug_emb) {
    int b     = blockIdx.x;
    int slice = b & 3;
    int d     = b >> 2;                        // < ND
    int wv    = threadIdx.x >> 6;
    int lane  = threadIdx.x & 63;
    int g     = lane >> 3;                     // node group 0..7
    int l     = lane & 7;                      // channel octet
    int c     = slice * 64 + (l << 3);
    int cb    = c << 1;
    __shared__ float s_red[4][64];
    int lo0 = __builtin_amdgcn_readfirstlane(drug_ptr[d]);
    int hi0 = __builtin_amdgcn_readfirstlane(drug_ptr[d + 1]);
    int len = hi0 - lo0;
    int lo = __builtin_amdgcn_readfirstlane(lo0 + (int)(((long long)len * wv) / 4));
    int hi = __builtin_amdgcn_readfirstlane(lo0 + (int)(((long long)len * (wv + 1)) / 4));
    f32x2 a2[4] = {};
    const char* hb = (const char*)h2bf;
    int deg   = hi - lo;
    int kfull = deg >> 3;
#pragma unroll 4
    for (int k = 0; k < kfull; k++) {
        int e   = lo + (k << 3) + g;
        int off = (sg_nodes[e] << 9) + cb;
        uint4 w = *(const uint4*)(hb + off);
        a2[0] += bfpair(w.x);
        a2[1] += bfpair(w.y);
        a2[2] += bfpair(w.z);
        a2[3] += bfpair(w.w);
    }
    int rem = deg & 7;
    if (rem) {
        int e   = lo + (kfull << 3) + g;
        float m = (g < rem) ? 1.f : 0.f;
        int ee  = (g < rem) ? e : (hi - 1);
        int off = (sg_nodes[ee] << 9) + cb;
        uint4 w = *(const uint4*)(hb + off);
        f32x2 m2; m2.x = m; m2.y = m;
        a2[0] += m2 * bfpair(w.x);
        a2[1] += m2 * bfpair(w.y);
        a2[2] += m2 * bfpair(w.z);
        a2[3] += m2 * bfpair(w.w);
    }
    float a[8] = {a2[0].x, a2[0].y, a2[1].x, a2[1].y, a2[2].x, a2[2].y, a2[3].x, a2[3].y};
#pragma unroll
    for (int i = 0; i < 8; i++) {
        a[i] += __shfl_xor(a[i], 8);
        a[i] += __shfl_xor(a[i], 16);
        a[i] += __shfl_xor(a[i], 32);
    }
    if (g == 0) {
        *(float4*)&s_red[wv][l << 3]       = make_float4(a[0], a[1], a[2], a[3]);
        *(float4*)&s_red[wv][(l << 3) + 4] = make_float4(a[4], a[5], a[6], a[7]);
    }
    __syncthreads();
    if (threadIdx.x < 64) {
        int t = threadIdx.x;
        float inv = 1.0f / (float)max(len, 1);
        float r = (s_red[0][t] + s_red[1][t]) + (s_red[2][t] + s_red[3][t]);
        drug_emb[(size_t)d * 256 + slice * 64 + t] = r * inv;
    }
}

// ---------------------------------------------------------------- dot head (wave per pair)
__global__ __launch_bounds__(256) void dot_kernel(const float* __restrict__ drug_emb,
                                                  const int* __restrict__ ddb,
                                                  float* __restrict__ out) {
    int wave = threadIdx.x >> 6;
    int lane = threadIdx.x & 63;
    int p = blockIdx.x * 4 + wave;
    if (p >= BDD) return;
    int a = ddb[p];
    int b = ddb[BDD + p];
    const float4* ea = (const float4*)(drug_emb + (size_t)a * 256);
    const float4* eb = (const float4*)(drug_emb + (size_t)b * 256);
    float4 va = ea[lane];
    float4 vb = eb[lane];
    float s = va.x * vb.x + va.y * vb.y + va.z * vb.z + va.w * vb.w;
#pragma unroll
    for (int off = 32; off > 0; off >>= 1) s += __shfl_down(s, off, 64);
    if (lane == 0) out[p] = s;
}

// ---------------------------------------------------------------- launcher
extern "C" void kernel_launch(void* const* d_in, const int* in_sizes, int n_in,
                              void* d_out, int out_size, void* d_ws, size_t ws_size,
                              hipStream_t stream) {
    const float* x        = (const float*)d_in[0];
    const int*   ddb      = (const int*)d_in[1];
    // d_in[2] edge_attr, d_in[3] edge_cell_lines: unused by reference
    const int*   sg_edge  = (const int*)d_in[4];   // [2, ESG]: src then dst
    const int*   sg_nodes = (const int*)d_in[5];
    const int*   sg_idx   = (const int*)d_in[6];
    const float* W1       = (const float*)d_in[7];
    const float* b1       = (const float*)d_in[8];
    const float* W2       = (const float*)d_in[9];
    const float* b2       = (const float*)d_in[10];
    float* out = (float*)d_out;

    char* ws = (char*)d_ws;
    size_t off = 0;
    auto alloc = [&](size_t bytes) -> void* {
        void* p = ws + off;
        off = (off + bytes + 255) & ~(size_t)255;
        return p;
    };
    int*   deg      = (int*)alloc(NP * sizeof(int));
    float* dinv     = (float*)alloc(NP * sizeof(float));
    int*   row_ptr  = (int*)alloc((NP + 1) * sizeof(int));
    int*   drug_ptr = (int*)alloc((ND + 1) * sizeof(int));
    unsigned short* rank16   = (unsigned short*)alloc((size_t)ESG * sizeof(unsigned short));
    unsigned short* hist_g   = (unsigned short*)alloc((size_t)NCH * NP * sizeof(unsigned short));
    unsigned short* csr_srcu = (unsigned short*)alloc((size_t)ESG * sizeof(unsigned short));
    unsigned short* bufAbf = (unsigned short*)alloc((size_t)NP * CHN * 2);        // bf16 hw twin (prescaled)
    float* h1       = (float*)alloc((size_t)NP * CHN * sizeof(float));
    unsigned short* h2bf   = (unsigned short*)alloc((size_t)NP * CHN * 2);
    float* drug_emb = (float*)alloc((size_t)ND * CHN * sizeof(float));
    unsigned short* bt1h = (unsigned short*)alloc((size_t)CHN * CHN * 2);
    unsigned short* bt1l = (unsigned short*)alloc((size_t)CHN * CHN * 2);
    unsigned short* bt2h = (unsigned short*)alloc((size_t)CHN * CHN * 2);
    unsigned short* bt2l = (unsigned short*)alloc((size_t)CHN * CHN * 2);

    const int* src = sg_edge;
    const int* dst = sg_edge + ESG;

    // counting-sort CSR build (LDS atomics only) + degree/row_ptr/dinv
    hist_rank_kernel<<<NCH, 256, 0, stream>>>(dst, rank16, hist_g);
    prefix_kernel<<<(NP + 255) / 256, 256, 0, stream>>>(hist_g, deg);
    scan_kernel<<<1, 256, 0, stream>>>(deg, row_ptr, dinv);

    // weight splits + drug_ptr table (single launch)
    wsplit2_kernel<<<2 * CHN + DP_BLKS, 256, 0, stream>>>(W1, W2, bt1h, bt1l,
                                                          bt2h, bt2l, sg_idx, drug_ptr);

    // fused: atomic-free CSR fill + MFMA gemm1 (A = x fp32, split in-register;
    // XCD-affine swizzled gemm blocks; bf16-only output)
    fill_gemm_kernel<<<GEMM_SW_BLK + FILL_BLK, 256, 0, stream>>>(src, dst, row_ptr,
                                                                 hist_g, rank16, csr_srcu,
                                                                 x, bt1h, bt1l,
                                                                 dinv, bufAbf);
    // layer 1: h1 = relu(agg + self + b1)   [self from bufAbf, bf16]
    spmm_kernel<<<NP, 256, 0, stream>>>(bufAbf, row_ptr, csr_srcu, dinv, b1,
                                        nullptr, h1, nullptr, 1);
    // layer 2: bufAbf = bf16(h1 @ W2 * dinv); h2bf = agg + self + b2 + h1
    gemm_kernel<<<GEMM_SW_BLK, 256, 0, stream>>>(h1, bt2h, bt2l, dinv,
                                                 bufAbf, NP);
    spmm_kernel<<<NP, 256, 0, stream>>>(bufAbf, row_ptr, csr_srcu, dinv, b2,
                                        h1, nullptr, h2bf, 0);
    // scatter-mean pooling (XCD-sliced, direct-indexed, drug_ptr table)
    pool_kernel<<<ND * 4, 256, 0, stream>>>(h2bf, sg_nodes, drug_ptr, drug_emb);
    // dot-product head
    dot_kernel<<<(BDD + 3) / 4, 256, 0, stream>>>(drug_emb, ddb, out);
}